// Round 1
// baseline (264.424 us; speedup 1.0000x reference)
//
#include <hip/hip_runtime.h>
#include <math.h>

// Problem constants (B=1, T=1024, E=512, H=8, D=64, M=8, R=1, P=32, CHUNK=128)
// Feature dim F = P*M = 256, flattened f = p*8 + m (consistent everywhere).

// ---------- GEMM: C[M,N] = A[M,K] @ W[N,K]^T + bias[N]  (64x64 tile, fp32) ----------
__global__ __launch_bounds__(256) void gemm_bias_kernel(
    const float* __restrict__ A, const float* __restrict__ W,
    const float* __restrict__ bias, float* __restrict__ C,
    int M, int N, int K)
{
    __shared__ float a_t[16][68];   // [k][row], padded to 68 (272B, 16B-aligned rows)
    __shared__ float w_t[16][68];
    const int tid = threadIdx.x;
    const int n0 = blockIdx.x * 64;
    const int m0 = blockIdx.y * 64;
    const int tx = tid & 15, ty = tid >> 4;
    const int lrow = tid >> 2;        // 0..63
    const int lk4  = (tid & 3) * 4;   // 0,4,8,12
    float acc[4][4];
#pragma unroll
    for (int i = 0; i < 4; ++i)
#pragma unroll
        for (int j = 0; j < 4; ++j) acc[i][j] = 0.f;

    for (int k0 = 0; k0 < K; k0 += 16) {
        float4 av = *(const float4*)&A[(m0 + lrow) * K + k0 + lk4];
        float4 wv = *(const float4*)&W[(n0 + lrow) * K + k0 + lk4];
        a_t[lk4 + 0][lrow] = av.x; a_t[lk4 + 1][lrow] = av.y;
        a_t[lk4 + 2][lrow] = av.z; a_t[lk4 + 3][lrow] = av.w;
        w_t[lk4 + 0][lrow] = wv.x; w_t[lk4 + 1][lrow] = wv.y;
        w_t[lk4 + 2][lrow] = wv.z; w_t[lk4 + 3][lrow] = wv.w;
        __syncthreads();
#pragma unroll
        for (int k = 0; k < 16; ++k) {
            float4 af = *(const float4*)&a_t[k][ty * 4];
            float4 wf = *(const float4*)&w_t[k][tx * 4];
            acc[0][0] += af.x * wf.x; acc[0][1] += af.x * wf.y;
            acc[0][2] += af.x * wf.z; acc[0][3] += af.x * wf.w;
            acc[1][0] += af.y * wf.x; acc[1][1] += af.y * wf.y;
            acc[1][2] += af.y * wf.z; acc[1][3] += af.y * wf.w;
            acc[2][0] += af.z * wf.x; acc[2][1] += af.z * wf.y;
            acc[2][2] += af.z * wf.z; acc[2][3] += af.z * wf.w;
            acc[3][0] += af.w * wf.x; acc[3][1] += af.w * wf.y;
            acc[3][2] += af.w * wf.z; acc[3][3] += af.w * wf.w;
        }
        __syncthreads();
    }
    float4 bv = *(const float4*)&bias[n0 + tx * 4];
#pragma unroll
    for (int i = 0; i < 4; ++i) {
        float4 o;
        o.x = acc[i][0] + bv.x; o.y = acc[i][1] + bv.y;
        o.z = acc[i][2] + bv.z; o.w = acc[i][3] + bv.w;
        *(float4*)&C[(m0 + ty * 4 + i) * N + n0 + tx * 4] = o;
    }
}

// ---------- Features: phi_q/phi_k[h][t][256] from qkv ----------
// One wave per (h,t); 4 waves/block.
__global__ __launch_bounds__(256) void features_kernel(
    const float* __restrict__ qkv, const float* __restrict__ omega,
    const float* __restrict__ W_poly, const float* __restrict__ qn,
    const float* __restrict__ qw, float* __restrict__ phi_q,
    float* __restrict__ phi_k)
{
    __shared__ float xn[4][2][64];
    __shared__ float poly[4][2][32];
    __shared__ float prf[4][2][8];
    const int tid = threadIdx.x;
    const int w = tid >> 6;
    const int lane = tid & 63;
    const int item = blockIdx.x * 4 + w;     // 0..8191
    const int h = item >> 10;
    const int t = item & 1023;

    float xq = qkv[t * 1536 + h * 64 + lane];
    float xk = qkv[t * 1536 + 512 + h * 64 + lane];
    float sq = xq * xq, sk = xk * xk;
#pragma unroll
    for (int o = 32; o; o >>= 1) { sq += __shfl_xor(sq, o); sk += __shfl_xor(sk, o); }
    float xnq = xq / fmaxf(sqrtf(sq), 1e-12f);
    float xnk = xk / fmaxf(sqrtf(sk), 1e-12f);
    xn[w][0][lane] = xnq;
    xn[w][1][lane] = xnk;
    __syncthreads();

    // poly: lanes 0..31 -> q (p=lane), lanes 32..63 -> k
    {
        const int which = lane >> 5;
        const int p = lane & 31;
        float pacc = 0.f;
#pragma unroll 8
        for (int d = 0; d < 64; ++d)
            pacc += xn[w][which][d] * W_poly[(h * 64 + d) * 32 + p];
        poly[w][which][p] = pacc;
    }
    // proj + prf: lanes 0..7 -> q (m=lane), lanes 8..15 -> k
    if (lane < 16) {
        const int wh2 = lane >> 3, m = lane & 7;
        float pr = 0.f;
#pragma unroll 8
        for (int d = 0; d < 64; ++d)
            pr += xn[w][wh2][d] * omega[(h * 64 + d) * 8 + m];
        float s0 = qn[0];
        float sqrt2s = sqrtf(2.f * fmaxf(s0, 0.f));
        float sqw = sqrtf(fmaxf(qw[0], 0.f));
        float z = fminf(fmaxf(pr * sqrt2s - s0, -20.f), 20.f);
        prf[w][wh2][m] = expf(z) * 0.3535533905932738f * sqw; // /sqrt(M) * sqrt(weight)
    }
    __syncthreads();

    // write phi: each lane writes 4 consecutive f = lane*4+j; p = lane>>1, m = (lane&1)*4+j
    const int pp = lane >> 1;
    const int mb = (lane & 1) * 4;
    float qp = poly[w][0][pp], kp = poly[w][1][pp];
    float4 oq, ok;
    oq.x = qp * prf[w][0][mb + 0]; oq.y = qp * prf[w][0][mb + 1];
    oq.z = qp * prf[w][0][mb + 2]; oq.w = qp * prf[w][0][mb + 3];
    ok.x = kp * prf[w][1][mb + 0]; ok.y = kp * prf[w][1][mb + 1];
    ok.z = kp * prf[w][1][mb + 2]; ok.w = kp * prf[w][1][mb + 3];
    *(float4*)&phi_q[((h << 10) + t) * 256 + lane * 4] = oq;
    *(float4*)&phi_k[((h << 10) + t) * 256 + lane * 4] = ok;
}

// ---------- Chunk sums: S_chunk[h][c][f][d] = sum_s phi_k[s][f]*v[s][d]; z_chunk[h][c][f] ----------
__global__ __launch_bounds__(256) void chunksum_kernel(
    const float* __restrict__ phi_k, const float* __restrict__ qkv,
    float* __restrict__ S_chunk, float* __restrict__ z_chunk)
{
    __shared__ float pk[32][256];  // [s][f]
    __shared__ float vv[32][64];   // [s][d]
    const int tid = threadIdx.x;
    const int h = blockIdx.x >> 3, c = blockIdx.x & 7;
    const int d = tid & 63, fg = tid >> 6;   // thread owns f in [fg*64, fg*64+64)
    float acc[64];
#pragma unroll
    for (int i = 0; i < 64; ++i) acc[i] = 0.f;
    float zacc = 0.f;

    for (int st = 0; st < 4; ++st) {
#pragma unroll
        for (int i = 0; i < 8; ++i) {   // 2048 float4 = 8192 floats
            int e4 = i * 256 + tid;
            int s = e4 >> 6;
            int f4 = (e4 & 63) * 4;
            *(float4*)&pk[s][f4] =
                *(const float4*)&phi_k[((h << 10) + c * 128 + st * 32 + s) * 256 + f4];
        }
#pragma unroll
        for (int i = 0; i < 8; ++i) {   // 2048 floats
            int e = i * 256 + tid;
            int s = e >> 6, dd = e & 63;
            vv[s][dd] = qkv[(c * 128 + st * 32 + s) * 1536 + 1024 + h * 64 + dd];
        }
        __syncthreads();
        for (int s = 0; s < 32; ++s) {
            float v_ = vv[s][d];
#pragma unroll
            for (int F = 0; F < 16; ++F) {
                float4 pv = *(const float4*)&pk[s][fg * 64 + F * 4];
                acc[F * 4 + 0] += pv.x * v_;
                acc[F * 4 + 1] += pv.y * v_;
                acc[F * 4 + 2] += pv.z * v_;
                acc[F * 4 + 3] += pv.w * v_;
            }
            zacc += pk[s][tid];
        }
        __syncthreads();
    }
#pragma unroll
    for (int F = 0; F < 64; ++F)
        S_chunk[(((h * 8 + c) * 256) + fg * 64 + F) * 64 + d] = acc[F];
    z_chunk[(h * 8 + c) * 256 + tid] = zacc;
}

// ---------- Exclusive prefix over chunks ----------
__global__ __launch_bounds__(256) void scan_kernel(
    const float* __restrict__ S_chunk, const float* __restrict__ z_chunk,
    float* __restrict__ S_prev, float* __restrict__ z_prev)
{
    int gid = blockIdx.x * 256 + threadIdx.x;
    if (gid < 8 * 256 * 64) {
        int h = gid >> 14;
        int r = gid & 16383;         // f*64+d
        float acc = 0.f;
#pragma unroll
        for (int c = 0; c < 8; ++c) {
            int idx = ((h * 8 + c) << 14) + r;
            S_prev[idx] = acc;
            acc += S_chunk[idx];
        }
    }
    if (gid < 2048) {
        int h = gid >> 8, f = gid & 255;
        float acc = 0.f;
#pragma unroll
        for (int c = 0; c < 8; ++c) {
            int idx = (h * 8 + c) * 256 + f;
            z_prev[idx] = acc;
            acc += z_chunk[idx];
        }
    }
}

// ---------- Attention output per (h, c, t-quarter): 32 rows x 64 d ----------
__global__ __launch_bounds__(256) void attn_kernel(
    const float* __restrict__ phi_q, const float* __restrict__ phi_k,
    const float* __restrict__ qkv, const float* __restrict__ S_prev,
    const float* __restrict__ z_prev, float* __restrict__ attn)
{
    __shared__ float v_lds[128 * 64];      // 32KB [s][d]
    __shared__ float A_lds[32 * 132];      // 16.9KB [t_local][s], stride 132
    __shared__ float phq_t[32][36];        // [f][t] (transposed), 4.6KB
    __shared__ float phk_t[32][132];       // [f][s] (transposed), 16.9KB
    __shared__ float Sst[32][64];          // [f][d], 8KB
    __shared__ float z_lds[256];
    __shared__ float den_lds[32];
    const int tid = threadIdx.x;
    const int h = blockIdx.x >> 3, c = blockIdx.x & 7;
    const int tb = blockIdx.y * 32;        // t-quarter base within chunk

    // stage v (full chunk) and z_prev
#pragma unroll
    for (int i = 0; i < 8; ++i) {          // 2048 float4
        int e4 = i * 256 + tid;
        int s = e4 >> 4;
        int d4 = (e4 & 15) * 4;
        *(float4*)&v_lds[s * 64 + d4] =
            *(const float4*)&qkv[(c * 128 + s) * 1536 + 1024 + h * 64 + d4];
    }
    z_lds[tid] = z_prev[(h * 8 + c) * 256 + tid];

    const int tt = tid >> 5, ss = tid & 31;    // A-phase mapping: rows tt*4.., cols ss*4..
    const int d = tid & 63, tg = tid >> 6;     // inter/intra mapping: d, rows tg*8..
    float acc[4][4];
    float acc2[8];
    float den_acc = 0.f;
#pragma unroll
    for (int i = 0; i < 4; ++i)
#pragma unroll
        for (int j = 0; j < 4; ++j) acc[i][j] = 0.f;
#pragma unroll
    for (int i = 0; i < 8; ++i) acc2[i] = 0.f;

    for (int ft = 0; ft < 8; ++ft) {
        const int f0 = ft * 32;
#pragma unroll
        for (int i = 0; i < 4; ++i) {      // phq_t: 1024 elems
            int e = i * 256 + tid;
            int t_ = e >> 5, f = e & 31;
            phq_t[f][t_] = phi_q[((h << 10) + c * 128 + tb + t_) * 256 + f0 + f];
        }
#pragma unroll
        for (int i = 0; i < 16; ++i) {     // phk_t: 4096 elems
            int e = i * 256 + tid;
            int s_ = e >> 5, f = e & 31;
            phk_t[f][s_] = phi_k[((h << 10) + c * 128 + s_) * 256 + f0 + f];
        }
#pragma unroll
        for (int i = 0; i < 8; ++i) {      // Sst: 2048 elems
            int e = i * 256 + tid;
            int f = e >> 6, dd = e & 63;
            Sst[f][dd] = S_prev[((h * 8 + c) * 256 + f0 + f) * 64 + dd];
        }
        __syncthreads();
#pragma unroll 4
        for (int f = 0; f < 32; ++f) {
            float4 av = *(const float4*)&phq_t[f][tt * 4];
            float4 bv = *(const float4*)&phk_t[f][ss * 4];
            acc[0][0] += av.x * bv.x; acc[0][1] += av.x * bv.y;
            acc[0][2] += av.x * bv.z; acc[0][3] += av.x * bv.w;
            acc[1][0] += av.y * bv.x; acc[1][1] += av.y * bv.y;
            acc[1][2] += av.y * bv.z; acc[1][3] += av.y * bv.w;
            acc[2][0] += av.z * bv.x; acc[2][1] += av.z * bv.y;
            acc[2][2] += av.z * bv.z; acc[2][3] += av.z * bv.w;
            acc[3][0] += av.w * bv.x; acc[3][1] += av.w * bv.y;
            acc[3][2] += av.w * bv.z; acc[3][3] += av.w * bv.w;
            float sval = Sst[f][d];
            float4 a0 = *(const float4*)&phq_t[f][tg * 8];
            float4 a1 = *(const float4*)&phq_t[f][tg * 8 + 4];
            acc2[0] += a0.x * sval; acc2[1] += a0.y * sval;
            acc2[2] += a0.z * sval; acc2[3] += a0.w * sval;
            acc2[4] += a1.x * sval; acc2[5] += a1.y * sval;
            acc2[6] += a1.z * sval; acc2[7] += a1.w * sval;
        }
        if (tid < 32) {
#pragma unroll
            for (int f = 0; f < 32; ++f)
                den_acc += phq_t[f][tid] * z_lds[f0 + f];
        }
        __syncthreads();
    }
    // dump A to LDS
#pragma unroll
    for (int i = 0; i < 4; ++i) {
        float4 o = make_float4(acc[i][0], acc[i][1], acc[i][2], acc[i][3]);
        *(float4*)&A_lds[(tt * 4 + i) * 132 + ss * 4] = o;
    }
    if (tid < 32) den_lds[tid] = den_acc;
    __syncthreads();

    // intra-chunk (causal, inclusive) + divide + store
#pragma unroll
    for (int i = 0; i < 8; ++i) {
        int tl = tg * 8 + i;          // local row 0..31
        int tcr = tb + tl;            // row within chunk 0..127
        float ctx = acc2[i];
        float den = den_lds[tl];
        for (int s = 0; s <= tcr; ++s) {
            float a = A_lds[tl * 132 + s];
            ctx += a * v_lds[s * 64 + d];
            den += a;
        }
        attn[(c * 128 + tcr) * 512 + h * 64 + d] = ctx / fmaxf(den, 1e-6f);
    }
}

extern "C" void kernel_launch(void* const* d_in, const int* in_sizes, int n_in,
                              void* d_out, int out_size, void* d_ws, size_t ws_size,
                              hipStream_t stream)
{
    const float* x      = (const float*)d_in[0];
    const float* W_qkv  = (const float*)d_in[1];
    const float* b_qkv  = (const float*)d_in[2];
    const float* W_out  = (const float*)d_in[3];
    const float* b_out  = (const float*)d_in[4];
    const float* omega  = (const float*)d_in[5];
    const float* W_poly = (const float*)d_in[6];
    const float* qn     = (const float*)d_in[7];
    const float* qw     = (const float*)d_in[8];
    float* out = (float*)d_out;

    float* ws    = (float*)d_ws;
    float* qkv   = ws;                    // 1024*1536
    float* phi_q = qkv + 1572864;         // 8*1024*256
    float* phi_k = phi_q + 2097152;       // 8*1024*256
    float* S_c   = phi_k + 2097152;       // 8*8*256*64
    float* z_c   = S_c + 1048576;         // 8*8*256
    float* S_p   = z_c + 16384;           // 8*8*256*64
    float* z_p   = S_p + 1048576;         // 8*8*256
    float* attn  = z_p + 16384;           // 1024*512

    gemm_bias_kernel<<<dim3(24, 16), 256, 0, stream>>>(x, W_qkv, b_qkv, qkv, 1024, 1536, 512);
    features_kernel<<<2048, 256, 0, stream>>>(qkv, omega, W_poly, qn, qw, phi_q, phi_k);
    chunksum_kernel<<<64, 256, 0, stream>>>(phi_k, qkv, S_c, z_c);
    scan_kernel<<<512, 256, 0, stream>>>(S_c, z_c, S_p, z_p);
    attn_kernel<<<dim3(64, 4), 256, 0, stream>>>(phi_q, phi_k, qkv, S_p, z_p, attn);
    gemm_bias_kernel<<<dim3(8, 16), 256, 0, stream>>>(attn, W_out, b_out, out, 1024, 512, 512);
}

// Round 4
// 198.206 us; speedup vs baseline: 1.3341x; 1.3341x over previous
//
#include <hip/hip_runtime.h>
#include <math.h>

// Problem constants (B=1, T=1024, E=512, H=8, D=64, M=8, R=1, P=32, CHUNK=128)
// Feature dim F = P*M = 256, flattened f = p*8 + m (consistent everywhere).

// ---------- GEMM: C[M,N] = A[M,K] @ W[N,K]^T + bias[N]  (64x64 tile, fp32) ----------
__global__ __launch_bounds__(256) void gemm_bias_kernel(
    const float* __restrict__ A, const float* __restrict__ W,
    const float* __restrict__ bias, float* __restrict__ C,
    int M, int N, int K)
{
    __shared__ float a_t[16][68];   // [k][row], padded to 68 (272B, 16B-aligned rows)
    __shared__ float w_t[16][68];
    const int tid = threadIdx.x;
    const int n0 = blockIdx.x * 64;
    const int m0 = blockIdx.y * 64;
    const int tx = tid & 15, ty = tid >> 4;
    const int lrow = tid >> 2;        // 0..63
    const int lk4  = (tid & 3) * 4;   // 0,4,8,12
    float acc[4][4];
#pragma unroll
    for (int i = 0; i < 4; ++i)
#pragma unroll
        for (int j = 0; j < 4; ++j) acc[i][j] = 0.f;

    for (int k0 = 0; k0 < K; k0 += 16) {
        float4 av = *(const float4*)&A[(m0 + lrow) * K + k0 + lk4];
        float4 wv = *(const float4*)&W[(n0 + lrow) * K + k0 + lk4];
        a_t[lk4 + 0][lrow] = av.x; a_t[lk4 + 1][lrow] = av.y;
        a_t[lk4 + 2][lrow] = av.z; a_t[lk4 + 3][lrow] = av.w;
        w_t[lk4 + 0][lrow] = wv.x; w_t[lk4 + 1][lrow] = wv.y;
        w_t[lk4 + 2][lrow] = wv.z; w_t[lk4 + 3][lrow] = wv.w;
        __syncthreads();
#pragma unroll
        for (int k = 0; k < 16; ++k) {
            float4 af = *(const float4*)&a_t[k][ty * 4];
            float4 wf = *(const float4*)&w_t[k][tx * 4];
            acc[0][0] += af.x * wf.x; acc[0][1] += af.x * wf.y;
            acc[0][2] += af.x * wf.z; acc[0][3] += af.x * wf.w;
            acc[1][0] += af.y * wf.x; acc[1][1] += af.y * wf.y;
            acc[1][2] += af.y * wf.z; acc[1][3] += af.y * wf.w;
            acc[2][0] += af.z * wf.x; acc[2][1] += af.z * wf.y;
            acc[2][2] += af.z * wf.z; acc[2][3] += af.z * wf.w;
            acc[3][0] += af.w * wf.x; acc[3][1] += af.w * wf.y;
            acc[3][2] += af.w * wf.z; acc[3][3] += af.w * wf.w;
        }
        __syncthreads();
    }
    float4 bv = *(const float4*)&bias[n0 + tx * 4];
#pragma unroll
    for (int i = 0; i < 4; ++i) {
        float4 o;
        o.x = acc[i][0] + bv.x; o.y = acc[i][1] + bv.y;
        o.z = acc[i][2] + bv.z; o.w = acc[i][3] + bv.w;
        *(float4*)&C[(m0 + ty * 4 + i) * N + n0 + tx * 4] = o;
    }
}

// ---------- Features: phi_q/phi_k[h][t][256] from qkv ----------
// One wave per (h,t); 4 waves/block.
__global__ __launch_bounds__(256) void features_kernel(
    const float* __restrict__ qkv, const float* __restrict__ omega,
    const float* __restrict__ W_poly, const float* __restrict__ qn,
    const float* __restrict__ qw, float* __restrict__ phi_q,
    float* __restrict__ phi_k)
{
    __shared__ float xn[4][2][64];
    __shared__ float poly[4][2][32];
    __shared__ float prf[4][2][8];
    const int tid = threadIdx.x;
    const int w = tid >> 6;
    const int lane = tid & 63;
    const int item = blockIdx.x * 4 + w;     // 0..8191
    const int h = item >> 10;
    const int t = item & 1023;

    float xq = qkv[t * 1536 + h * 64 + lane];
    float xk = qkv[t * 1536 + 512 + h * 64 + lane];
    float sq = xq * xq, sk = xk * xk;
#pragma unroll
    for (int o = 32; o; o >>= 1) { sq += __shfl_xor(sq, o); sk += __shfl_xor(sk, o); }
    float xnq = xq / fmaxf(sqrtf(sq), 1e-12f);
    float xnk = xk / fmaxf(sqrtf(sk), 1e-12f);
    xn[w][0][lane] = xnq;
    xn[w][1][lane] = xnk;
    __syncthreads();

    // poly: lanes 0..31 -> q (p=lane), lanes 32..63 -> k
    {
        const int which = lane >> 5;
        const int p = lane & 31;
        float pacc = 0.f;
#pragma unroll 8
        for (int d = 0; d < 64; ++d)
            pacc += xn[w][which][d] * W_poly[(h * 64 + d) * 32 + p];
        poly[w][which][p] = pacc;
    }
    // proj + prf: lanes 0..7 -> q (m=lane), lanes 8..15 -> k
    if (lane < 16) {
        const int wh2 = lane >> 3, m = lane & 7;
        float pr = 0.f;
#pragma unroll 8
        for (int d = 0; d < 64; ++d)
            pr += xn[w][wh2][d] * omega[(h * 64 + d) * 8 + m];
        float s0 = qn[0];
        float sqrt2s = sqrtf(2.f * fmaxf(s0, 0.f));
        float sqw = sqrtf(fmaxf(qw[0], 0.f));
        float z = fminf(fmaxf(pr * sqrt2s - s0, -20.f), 20.f);
        prf[w][wh2][m] = expf(z) * 0.3535533905932738f * sqw; // /sqrt(M) * sqrt(weight)
    }
    __syncthreads();

    // write phi: each lane writes 4 consecutive f = lane*4+j; p = lane>>1, m = (lane&1)*4+j
    const int pp = lane >> 1;
    const int mb = (lane & 1) * 4;
    float qp = poly[w][0][pp], kp = poly[w][1][pp];
    float4 oq, ok;
    oq.x = qp * prf[w][0][mb + 0]; oq.y = qp * prf[w][0][mb + 1];
    oq.z = qp * prf[w][0][mb + 2]; oq.w = qp * prf[w][0][mb + 3];
    ok.x = kp * prf[w][1][mb + 0]; ok.y = kp * prf[w][1][mb + 1];
    ok.z = kp * prf[w][1][mb + 2]; ok.w = kp * prf[w][1][mb + 3];
    *(float4*)&phi_q[((h << 10) + t) * 256 + lane * 4] = oq;
    *(float4*)&phi_k[((h << 10) + t) * 256 + lane * 4] = ok;
}

// ---------- Chunk sums: S_chunk[h][c][f][d] = sum_s phi_k[s][f]*v[s][d]; z_chunk[h][c][f] ----------
// Re-tiled: grid = (h,c,fg) = 8*8*4 = 256 blocks; block computes a 64(f) x 64(d) tile
// with a 4x4 micro-tile per thread (outer-product form, VALU-bound).
__global__ __launch_bounds__(256) void chunksum_kernel(
    const float* __restrict__ phi_k, const float* __restrict__ qkv,
    float* __restrict__ S_chunk, float* __restrict__ z_chunk)
{
    __shared__ float pk[128][64];  // [s][f_local]  32KB
    __shared__ float vv[128][64];  // [s][d]        32KB
    const int tid = threadIdx.x;
    const int h  = blockIdx.x >> 5;
    const int c  = (blockIdx.x >> 2) & 7;
    const int fg = blockIdx.x & 3;
    const int f0 = fg * 64;

    // stage pk slice: 128 x 64 floats = 2048 float4
#pragma unroll
    for (int i = 0; i < 8; ++i) {
        int e4 = i * 256 + tid;
        int s = e4 >> 4;
        int f4 = (e4 & 15) * 4;
        *(float4*)&pk[s][f4] =
            *(const float4*)&phi_k[((h << 10) + c * 128 + s) * 256 + f0 + f4];
    }
    // stage v: 128 x 64 floats
#pragma unroll
    for (int i = 0; i < 8; ++i) {
        int e4 = i * 256 + tid;
        int s = e4 >> 4;
        int d4 = (e4 & 15) * 4;
        *(float4*)&vv[s][d4] =
            *(const float4*)&qkv[(c * 128 + s) * 1536 + 1024 + h * 64 + d4];
    }
    __syncthreads();

    const int tx = tid & 15;      // d-block: d = tx*4 ..
    const int ty = tid >> 4;      // f-block: f_local = ty*4 ..
    float acc[4][4];
#pragma unroll
    for (int i = 0; i < 4; ++i)
#pragma unroll
        for (int j = 0; j < 4; ++j) acc[i][j] = 0.f;

    for (int s = 0; s < 128; ++s) {
        float4 pv = *(const float4*)&pk[s][ty * 4];
        float4 v4 = *(const float4*)&vv[s][tx * 4];
        acc[0][0] += pv.x * v4.x; acc[0][1] += pv.x * v4.y;
        acc[0][2] += pv.x * v4.z; acc[0][3] += pv.x * v4.w;
        acc[1][0] += pv.y * v4.x; acc[1][1] += pv.y * v4.y;
        acc[1][2] += pv.y * v4.z; acc[1][3] += pv.y * v4.w;
        acc[2][0] += pv.z * v4.x; acc[2][1] += pv.z * v4.y;
        acc[2][2] += pv.z * v4.z; acc[2][3] += pv.z * v4.w;
        acc[3][0] += pv.w * v4.x; acc[3][1] += pv.w * v4.y;
        acc[3][2] += pv.w * v4.z; acc[3][3] += pv.w * v4.w;
    }

    // z for this block's 64 f values (wave 0 only; pk stable, no sync needed)
    if (tid < 64) {
        float zacc = 0.f;
        for (int s = 0; s < 128; ++s) zacc += pk[s][tid];
        z_chunk[(h * 8 + c) * 256 + f0 + tid] = zacc;
    }

#pragma unroll
    for (int i = 0; i < 4; ++i) {
        float4 o = make_float4(acc[i][0], acc[i][1], acc[i][2], acc[i][3]);
        *(float4*)&S_chunk[((h * 8 + c) * 256 + f0 + ty * 4 + i) * 64 + tx * 4] = o;
    }
}

// ---------- Exclusive prefix over chunks ----------
__global__ __launch_bounds__(256) void scan_kernel(
    const float* __restrict__ S_chunk, const float* __restrict__ z_chunk,
    float* __restrict__ S_prev, float* __restrict__ z_prev)
{
    int gid = blockIdx.x * 256 + threadIdx.x;
    if (gid < 8 * 256 * 64) {
        int h = gid >> 14;
        int r = gid & 16383;         // f*64+d
        float acc = 0.f;
#pragma unroll
        for (int c = 0; c < 8; ++c) {
            int idx = ((h * 8 + c) << 14) + r;
            S_prev[idx] = acc;
            acc += S_chunk[idx];
        }
    }
    if (gid < 2048) {
        int h = gid >> 8, f = gid & 255;
        float acc = 0.f;
#pragma unroll
        for (int c = 0; c < 8; ++c) {
            int idx = (h * 8 + c) * 256 + f;
            z_prev[idx] = acc;
            acc += z_chunk[idx];
        }
    }
}

// ---------- Attention output per (h, c, t-quarter): 32 rows x 64 d ----------
__global__ __launch_bounds__(256) void attn_kernel(
    const float* __restrict__ phi_q, const float* __restrict__ phi_k,
    const float* __restrict__ qkv, const float* __restrict__ S_prev,
    const float* __restrict__ z_prev, float* __restrict__ attn)
{
    __shared__ float v_lds[128 * 64];      // 32KB [s][d]
    __shared__ float A_lds[32 * 132];      // 16.9KB [t_local][s], stride 132
    __shared__ float phq_t[32][36];        // [f][t] (transposed), 4.6KB
    __shared__ float phk_t[32][132];       // [f][s] (transposed), 16.9KB
    __shared__ float Sst[32][64];          // [f][d], 8KB
    __shared__ float z_lds[256];
    __shared__ float den_lds[32];
    const int tid = threadIdx.x;
    const int h = blockIdx.x >> 3, c = blockIdx.x & 7;
    const int tb = blockIdx.y * 32;        // t-quarter base within chunk

    // stage v (full chunk) and z_prev
#pragma unroll
    for (int i = 0; i < 8; ++i) {          // 2048 float4
        int e4 = i * 256 + tid;
        int s = e4 >> 4;
        int d4 = (e4 & 15) * 4;
        *(float4*)&v_lds[s * 64 + d4] =
            *(const float4*)&qkv[(c * 128 + s) * 1536 + 1024 + h * 64 + d4];
    }
    z_lds[tid] = z_prev[(h * 8 + c) * 256 + tid];

    const int tt = tid >> 5, ss = tid & 31;    // A-phase mapping: rows tt*4.., cols ss*4..
    const int d = tid & 63, tg = tid >> 6;     // inter/intra mapping: d, rows tg*8..
    float acc[4][4];
    float acc2[8];
    float den_acc = 0.f;
#pragma unroll
    for (int i = 0; i < 4; ++i)
#pragma unroll
        for (int j = 0; j < 4; ++j) acc[i][j] = 0.f;
#pragma unroll
    for (int i = 0; i < 8; ++i) acc2[i] = 0.f;

    for (int ft = 0; ft < 8; ++ft) {
        const int f0 = ft * 32;
#pragma unroll
        for (int i = 0; i < 4; ++i) {      // phq_t: 1024 elems
            int e = i * 256 + tid;
            int t_ = e >> 5, f = e & 31;
            phq_t[f][t_] = phi_q[((h << 10) + c * 128 + tb + t_) * 256 + f0 + f];
        }
#pragma unroll
        for (int i = 0; i < 16; ++i) {     // phk_t: 4096 elems
            int e = i * 256 + tid;
            int s_ = e >> 5, f = e & 31;
            phk_t[f][s_] = phi_k[((h << 10) + c * 128 + s_) * 256 + f0 + f];
        }
#pragma unroll
        for (int i = 0; i < 8; ++i) {      // Sst: 2048 elems
            int e = i * 256 + tid;
            int f = e >> 6, dd = e & 63;
            Sst[f][dd] = S_prev[((h * 8 + c) * 256 + f0 + f) * 64 + dd];
        }
        __syncthreads();
#pragma unroll 4
        for (int f = 0; f < 32; ++f) {
            float4 av = *(const float4*)&phq_t[f][tt * 4];
            float4 bv = *(const float4*)&phk_t[f][ss * 4];
            acc[0][0] += av.x * bv.x; acc[0][1] += av.x * bv.y;
            acc[0][2] += av.x * bv.z; acc[0][3] += av.x * bv.w;
            acc[1][0] += av.y * bv.x; acc[1][1] += av.y * bv.y;
            acc[1][2] += av.y * bv.z; acc[1][3] += av.y * bv.w;
            acc[2][0] += av.z * bv.x; acc[2][1] += av.z * bv.y;
            acc[2][2] += av.z * bv.z; acc[2][3] += av.z * bv.w;
            acc[3][0] += av.w * bv.x; acc[3][1] += av.w * bv.y;
            acc[3][2] += av.w * bv.z; acc[3][3] += av.w * bv.w;
            float sval = Sst[f][d];
            float4 a0 = *(const float4*)&phq_t[f][tg * 8];
            float4 a1 = *(const float4*)&phq_t[f][tg * 8 + 4];
            acc2[0] += a0.x * sval; acc2[1] += a0.y * sval;
            acc2[2] += a0.z * sval; acc2[3] += a0.w * sval;
            acc2[4] += a1.x * sval; acc2[5] += a1.y * sval;
            acc2[6] += a1.z * sval; acc2[7] += a1.w * sval;
        }
        if (tid < 32) {
#pragma unroll
            for (int f = 0; f < 32; ++f)
                den_acc += phq_t[f][tid] * z_lds[f0 + f];
        }
        __syncthreads();
    }
    // dump A to LDS
#pragma unroll
    for (int i = 0; i < 4; ++i) {
        float4 o = make_float4(acc[i][0], acc[i][1], acc[i][2], acc[i][3]);
        *(float4*)&A_lds[(tt * 4 + i) * 132 + ss * 4] = o;
    }
    if (tid < 32) den_lds[tid] = den_acc;
    __syncthreads();

    // intra-chunk (causal, inclusive) + divide + store
#pragma unroll
    for (int i = 0; i < 8; ++i) {
        int tl = tg * 8 + i;          // local row 0..31
        int tcr = tb + tl;            // row within chunk 0..127
        float ctx = acc2[i];
        float den = den_lds[tl];
        for (int s = 0; s <= tcr; ++s) {
            float a = A_lds[tl * 132 + s];
            ctx += a * v_lds[s * 64 + d];
            den += a;
        }
        attn[(c * 128 + tcr) * 512 + h * 64 + d] = ctx / fmaxf(den, 1e-6f);
    }
}

extern "C" void kernel_launch(void* const* d_in, const int* in_sizes, int n_in,
                              void* d_out, int out_size, void* d_ws, size_t ws_size,
                              hipStream_t stream)
{
    const float* x      = (const float*)d_in[0];
    const float* W_qkv  = (const float*)d_in[1];
    const float* b_qkv  = (const float*)d_in[2];
    const float* W_out  = (const float*)d_in[3];
    const float* b_out  = (const float*)d_in[4];
    const float* omega  = (const float*)d_in[5];
    const float* W_poly = (const float*)d_in[6];
    const float* qn     = (const float*)d_in[7];
    const float* qw     = (const float*)d_in[8];
    float* out = (float*)d_out;

    float* ws    = (float*)d_ws;
    float* qkv   = ws;                    // 1024*1536
    float* phi_q = qkv + 1572864;         // 8*1024*256
    float* phi_k = phi_q + 2097152;       // 8*1024*256
    float* S_c   = phi_k + 2097152;       // 8*8*256*64
    float* z_c   = S_c + 1048576;         // 8*8*256
    float* S_p   = z_c + 16384;           // 8*8*256*64
    float* z_p   = S_p + 1048576;         // 8*8*256
    float* attn  = z_p + 16384;           // 1024*512

    gemm_bias_kernel<<<dim3(24, 16), 256, 0, stream>>>(x, W_qkv, b_qkv, qkv, 1024, 1536, 512);
    features_kernel<<<2048, 256, 0, stream>>>(qkv, omega, W_poly, qn, qw, phi_q, phi_k);
    chunksum_kernel<<<256, 256, 0, stream>>>(phi_k, qkv, S_c, z_c);
    scan_kernel<<<512, 256, 0, stream>>>(S_c, z_c, S_p, z_p);
    attn_kernel<<<dim3(64, 4), 256, 0, stream>>>(phi_q, phi_k, qkv, S_p, z_p, attn);
    gemm_bias_kernel<<<dim3(8, 16), 256, 0, stream>>>(attn, W_out, b_out, out, 1024, 512, 512);
}